// Round 6
// baseline (4452.241 us; speedup 1.0000x reference)
//
#include <hip/hip_runtime.h>
#include <hip/hip_bf16.h>
#include <cmath>

// L=128, B=256, H=256, C=17, Y=16, N_SUB=2
#define L_   128
#define B_   256
#define H_   256
#define C_   17
#define Y_   16
#define NSUB 254
#define NBLK 256

typedef short bf16x8 __attribute__((ext_vector_type(8)));
typedef float f32x4  __attribute__((ext_vector_type(4)));
typedef unsigned short u16;
typedef unsigned int   u32;

// ---- workspace byte offsets ------------------------------------------------
// dXr [254][256][20] f32; W2 frag planes; zF frag planes [2buf][4bq][16384]u16;
// W1 frag planes [16mt][8kt][512]u16; dec frag planes [8kt][512]u16; barriers.
#define OFF_DXR  0u
#define OFF_W2H  5201920u
#define OFF_W2L  10444800u
#define OFF_ZFH  15687680u
#define OFF_ZFL  15949824u
#define OFF_W1H  16211968u
#define OFF_W1L  16343040u
#define OFF_DEH  16474112u
#define OFF_DEL  16482304u
#define OFF_BAR  16490496u

__device__ __forceinline__ float fast_tanh(float x) {
  float e = __expf(2.0f * x);
  return 1.0f - __fdividef(2.0f, e + 1.0f);
}

__device__ __forceinline__ void bsplit(float x, u16& hi, u16& lo) {
  __hip_bfloat16 h = __float2bfloat16(x);
  float hf = __bfloat162float(h);
  __hip_bfloat16 l = __float2bfloat16(x - hf);
  hi = *(u16*)&h;
  lo = *(u16*)&l;
}

// ---- coherent-bypass helpers (data travels via the coherent point) ---------
__device__ __forceinline__ void ld16_coh(f32x4 r[16], const f32x4* a, const f32x4* b) {
  asm volatile(
    "global_load_dwordx4 %0, %16, off sc0 sc1\n\t"
    "global_load_dwordx4 %1, %17, off sc0 sc1\n\t"
    "global_load_dwordx4 %2, %18, off sc0 sc1\n\t"
    "global_load_dwordx4 %3, %19, off sc0 sc1\n\t"
    "global_load_dwordx4 %4, %20, off sc0 sc1\n\t"
    "global_load_dwordx4 %5, %21, off sc0 sc1\n\t"
    "global_load_dwordx4 %6, %22, off sc0 sc1\n\t"
    "global_load_dwordx4 %7, %23, off sc0 sc1\n\t"
    "global_load_dwordx4 %8, %24, off sc0 sc1\n\t"
    "global_load_dwordx4 %9, %25, off sc0 sc1\n\t"
    "global_load_dwordx4 %10, %26, off sc0 sc1\n\t"
    "global_load_dwordx4 %11, %27, off sc0 sc1\n\t"
    "global_load_dwordx4 %12, %28, off sc0 sc1\n\t"
    "global_load_dwordx4 %13, %29, off sc0 sc1\n\t"
    "global_load_dwordx4 %14, %30, off sc0 sc1\n\t"
    "global_load_dwordx4 %15, %31, off sc0 sc1\n\t"
    "s_waitcnt vmcnt(0)"
    : "=&v"(r[0]), "=&v"(r[1]), "=&v"(r[2]), "=&v"(r[3]),
      "=&v"(r[4]), "=&v"(r[5]), "=&v"(r[6]), "=&v"(r[7]),
      "=&v"(r[8]), "=&v"(r[9]), "=&v"(r[10]), "=&v"(r[11]),
      "=&v"(r[12]), "=&v"(r[13]), "=&v"(r[14]), "=&v"(r[15])
    : "v"(a), "v"(a + 256), "v"(a + 512), "v"(a + 768),
      "v"(a + 1024), "v"(a + 1280), "v"(a + 1536), "v"(a + 1792),
      "v"(b), "v"(b + 256), "v"(b + 512), "v"(b + 768),
      "v"(b + 1024), "v"(b + 1280), "v"(b + 1536), "v"(b + 1792)
    : "memory");
}

__device__ __forceinline__ void st_coh_u16(u16* p, u32 v) {
  asm volatile("global_store_short %0, %1, off sc0 sc1" :: "v"(p), "v"(v) : "memory");
}

// ---------------------------------------------------------------------------
// dXr[sub][b][c(20 pad)] = dX * (h/2)
__global__ void k_dx(const float* __restrict__ ts, const float* __restrict__ us,
                     float* __restrict__ dXr) {
  int idx = blockIdx.x * 256 + threadIdx.x;     // 1,300,480 exact
  int c   = idx % 20;
  int t2  = idx / 20;
  int b   = t2 & 255;
  int sub = t2 >> 8;
  if (c >= C_) { dXr[idx] = 0.f; return; }
  int s = sub >> 1, j = sub & 1;
  float t_s = ts[s * B_], t_n = ts[(s + 1) * B_];
  float h = t_n - t_s;
  float xi, xn;
  if (c == 0) { xi = ts[s * B_ + b]; xn = ts[(s + 1) * B_ + b]; }
  else {
    xi = us[(size_t)s       * 4096 + b * 16 + (c - 1)];
    xn = us[(size_t)(s + 1) * 4096 + b * 16 + (c - 1)];
  }
  float mn = (xn - xi) / h;
  float mi;
  if (s == 0) mi = mn;
  else {
    float hp = t_s - ts[(s - 1) * B_];
    float xp = (c == 0) ? ts[(s - 1) * B_ + b]
                        : us[(size_t)(s - 1) * 4096 + b * 16 + (c - 1)];
    mi = (xi - xp) / hp;
  }
  float c2 = 3.f * (xn - xi) / (h * h) - (2.f * mi + mn) / h;
  float c3 = 2.f * (xi - xn) / (h * h * h) + (mi + mn) / (h * h);
  float u  = j ? 0.5f * h : 0.f;
  float dX = mi + 2.f * c2 * u + 3.f * c3 * u * u;
  dXr[idx] = dX * 0.5f * h;
}

// ---------------------------------------------------------------------------
// W2 A-fragments (verified in R4/R5): A[m=col(80 pad20)][k=256], hi/lo planes.
__global__ void k_w2f(const float* __restrict__ W2,
                      u16* __restrict__ W2H, u16* __restrict__ W2L) {
  int idx = blockIdx.x * 256 + threadIdx.x;     // 2,621,440 exact
  int e = idx & 7, t = idx >> 3;
  int lane = t & 63; t >>= 6;
  int mt = t % 5;  t /= 5;
  int kt = t & 1;  t >>= 1;
  int kq = t & 3;  t >>= 2;
  int hq = t;                                   // 0..63 (role: j)
  int col = mt * 16 + (lane & 15);
  int hl = col / 20, c = col - hl * 20;
  int k = kq * 64 + kt * 32 + 4 * (lane >> 4) + (e & 3) + 16 * (e >> 2);
  float v = (c < C_) ? W2[(size_t)k * (H_ * C_) + (hq * 4 + hl) * C_ + c] : 0.f;
  u16 hi, lo; bsplit(v, hi, lo);
  W2H[idx] = hi; W2L[idx] = lo;
}

// W1 A-fragments: A[m=ho(256)][k=h_in(256)], [mt 16][kt 8][lane 64][e 8].
__global__ void k_w1f(const float* __restrict__ W1,
                      u16* __restrict__ W1H, u16* __restrict__ W1L) {
  int idx = blockIdx.x * 256 + threadIdx.x;     // 65536
  int e = idx & 7, lane = (idx >> 3) & 63, kt = (idx >> 9) & 7, mtg = idx >> 12;
  int m = mtg * 16 + (lane & 15);
  int k = kt * 32 + 4 * (lane >> 4) + (e & 3) + 16 * (e >> 2);
  float v = W1[k * 256 + m];
  u16 hi, lo; bsplit(v, hi, lo);
  W1H[idx] = hi; W1L[idx] = lo;
}

// dec_W A-fragments: A[m=y(16)][k=h(256)], [kt 8][lane 64][e 8].
__global__ void k_def(const float* __restrict__ decW,
                      u16* __restrict__ DH, u16* __restrict__ DL) {
  int idx = blockIdx.x * 256 + threadIdx.x;     // 4096
  int e = idx & 7, lane = (idx >> 3) & 63, kt = idx >> 9;
  int y = lane & 15;
  int k = kt * 32 + 4 * (lane >> 4) + (e & 3) + 16 * (e >> 2);
  float v = decW[k * 16 + y];
  u16 hi, lo; bsplit(v, hi, lo);
  DH[idx] = hi; DL[idx] = lo;
}

// z0 frags (buf0): [4bq][8kt][4nt][64][8], z0[h][b] = enc_b[h].
__global__ void k_initF(const float* __restrict__ enc_b,
                        u16* __restrict__ ZH, u16* __restrict__ ZL) {
  int idx = blockIdx.x * 256 + threadIdx.x;     // 65536
  int e = idx & 7, lane = (idx >> 3) & 63;
  int kt = (idx >> 11) & 7;
  int h = kt * 32 + 4 * (lane >> 4) + (e & 3) + 16 * (e >> 2);
  float v = enc_b[h];
  u16 hi, lo; bsplit(v, hi, lo);
  ZH[idx] = hi; ZL[idx] = lo;
}

__global__ void k_bar0(u32* bar) {
  if (threadIdx.x < 4) bar[threadIdx.x * 128] = 0u;
}

// ---------------------------------------------------------------------------
// Fence-free group barrier (R5-verified): monotonic counter, RELAXED agent
// atomics; tid0's vmcnt(0) drains wave0's coherent stores before arrival.
__device__ __forceinline__ void gbar(u32* cnt, u32 target) {
  __syncthreads();
  if (threadIdx.x == 0) {
    asm volatile("s_waitcnt vmcnt(0)" ::: "memory");
    __hip_atomic_fetch_add(cnt, 1u, __ATOMIC_RELAXED, __HIP_MEMORY_SCOPE_AGENT);
    u32 guard = 0;
    while (__hip_atomic_load(cnt, __ATOMIC_RELAXED, __HIP_MEMORY_SCOPE_AGENT) < target) {
      __builtin_amdgcn_s_sleep(2);
      if (++guard > (1u << 20)) break;          // failsafe vs hard hang
    }
  }
  __syncthreads();
}

// ---------------------------------------------------------------------------
// Persistent kernel: 256 blocks (bq = blk&3 owns 64 b, j = blk>>2 owns 4 h of
// z/W2), 4 waves (wq). Per substep: gather z frags (ONE coherent RT) -> every
// block redundantly computes full phase A via MFMA (wave wq owns ho-quarter)
// -> in-wave repack to phase-B B-frags through local LDS -> phase B MFMA with
// persistent W2 frags -> epilogue (wave0) -> z frag stores -> ONE barrier.
__global__ __launch_bounds__(256, 1)
void k_ode2(char* __restrict__ wsb,
            const float* __restrict__ f_b1, const float* __restrict__ f_b2,
            const float* __restrict__ dec_b, float* __restrict__ out) {
  const int tid = threadIdx.x;
  const int lane = tid & 63, wq = tid >> 6;
  const int bq = blockIdx.x & 3, j = blockIdx.x >> 2;
  const int gg = lane >> 4, c16 = lane & 15;

  float* dXr = (float*)(wsb + OFF_DXR);
  u16* zFH = (u16*)(wsb + OFF_ZFH);
  u16* zFL = (u16*)(wsb + OFF_ZFL);
  u32* mycnt = (u32*)(wsb + OFF_BAR) + (size_t)bq * 128;
  u32  bt = 64;

  // LDS: zF hi/lo (64KB) | hdnF hi/lo (64KB) | b1L | b2L.
  // redB unions zF (dead after phase A); redD unions hdnF (dead before phase A).
  __shared__ __align__(16) char smem[132480];
  const bf16x8* zHl  = (const bf16x8*)(smem);
  const bf16x8* zLl  = (const bf16x8*)(smem + 32768);
  const bf16x8* hHl  = (const bf16x8*)(smem + 65536);
  const bf16x8* hLl  = (const bf16x8*)(smem + 98304);
  float* redB = (float*)smem;                       // [(q*64+lane)*84 + t*4]
  float* redD = (float*)(smem + 65536);             // [3][64][16]
  float* b1L  = (float*)(smem + 131072);            // [256]
  float* b2L  = (float*)(smem + 132096);            // [80]

  b1L[tid] = f_b1[tid];
  if (tid < 80) { int hl = tid / 20, c = tid - hl * 20;
                  b2L[tid] = (c < C_) ? f_b2[(j * 4 + hl) * C_ + c] : 0.f; }

  // persistent W2 A-fragments (hi/lo), this wave's K-quarter
  bf16x8 wHi[2][5], wLo[2][5];
  {
    const bf16x8* WH = (const bf16x8*)(wsb + OFF_W2H);
    const bf16x8* WL = (const bf16x8*)(wsb + OFF_W2L);
    #pragma unroll
    for (int ktl = 0; ktl < 2; ++ktl)
      #pragma unroll
      for (int mt = 0; mt < 5; ++mt) {
        int f = ((((j * 4 + wq) * 2 + ktl) * 5 + mt) << 6) + lane;
        wHi[ktl][mt] = WH[f];
        wLo[ktl][mt] = WL[f];
      }
  }

  // block-private fp32 master copy of owned z: (h = j*4+gg, b = bq*64+nt*16+c16)
  float zreg[4];
  {
    float z0 = b2L[0];  // placeholder ordering; real init below (enc_b via b1? no)
  }
  // z0 = enc_b[h]; enc_b not passed -> recover from zF frags? Instead pass via
  // dec_b? Simplest: read from zF buf0 global (hi+lo) for our own slot.
  {
    int kt = j >> 3;
    int lp = c16 + 16 * (j & 3);
    int e  = gg + 4 * ((j >> 2) & 1);
    #pragma unroll
    for (int nt = 0; nt < 4; ++nt) {
      int idx = ((kt * 4 + nt) * 64 + lp) * 8 + e;
      float hi = __bfloat162float(*(__hip_bfloat16*)(zFH + bq * 16384 + idx));
      float lo = __bfloat162float(*(__hip_bfloat16*)(zFL + bq * 16384 + idx));
      zreg[nt] = hi + lo;
    }
  }
  __syncthreads();

  for (int sub = 0; ; ++sub) {
    // ---- gather z frags (hi+lo, 64KB/block) in ONE coherent round trip ----
    {
      const f32x4* gH = (const f32x4*)(zFH + ((size_t)(sub & 1) * 4 + bq) * 16384) + tid;
      const f32x4* gL = (const f32x4*)(zFL + ((size_t)(sub & 1) * 4 + bq) * 16384) + tid;
      f32x4 r[16];
      ld16_coh(r, gH, gL);
      #pragma unroll
      for (int k = 0; k < 8; ++k) {
        *(f32x4*)(smem + (tid + k * 256) * 16)         = r[k];
        *(f32x4*)(smem + 32768 + (tid + k * 256) * 16) = r[8 + k];
      }
    }
    __syncthreads();

    // ---- decode out[sub/2] on even substeps (MFMA, redundant; j==0 stores) ----
    if ((sub & 1) == 0) {
      const bf16x8* dH = (const bf16x8*)(wsb + OFF_DEH);
      const bf16x8* dL = (const bf16x8*)(wsb + OFF_DEL);
      f32x4 aD[4];
      #pragma unroll
      for (int nt = 0; nt < 4; ++nt) aD[nt] = (f32x4){0.f, 0.f, 0.f, 0.f};
      #pragma unroll
      for (int ktl = 0; ktl < 2; ++ktl) {
        int kt = wq * 2 + ktl;
        bf16x8 dh = dH[kt * 64 + lane], dl = dL[kt * 64 + lane];
        #pragma unroll
        for (int nt = 0; nt < 4; ++nt) {
          int li = (kt * 4 + nt) * 64 + lane;
          bf16x8 zh = zHl[li], zl = zLl[li];
          aD[nt] = __builtin_amdgcn_mfma_f32_16x16x32_bf16(dh, zh, aD[nt], 0, 0, 0);
          aD[nt] = __builtin_amdgcn_mfma_f32_16x16x32_bf16(dh, zl, aD[nt], 0, 0, 0);
          aD[nt] = __builtin_amdgcn_mfma_f32_16x16x32_bf16(dl, zh, aD[nt], 0, 0, 0);
        }
      }
      if (wq) {
        float* rp = redD + ((wq - 1) * 64 + lane) * 16;
        #pragma unroll
        for (int nt = 0; nt < 4; ++nt) *(f32x4*)(rp + nt * 4) = aD[nt];
      }
      __syncthreads();
      if (wq == 0 && j == 0) {
        #pragma unroll
        for (int q = 0; q < 3; ++q) {
          const float* rp = redD + (q * 64 + lane) * 16;
          #pragma unroll
          for (int nt = 0; nt < 4; ++nt) aD[nt] += *(const f32x4*)(rp + nt * 4);
        }
        #pragma unroll
        for (int nt = 0; nt < 4; ++nt) {
          int brow = bq * 64 + nt * 16 + c16;
          #pragma unroll
          for (int r = 0; r < 4; ++r)
            out[(size_t)(sub >> 1) * 4096 + brow * 16 + 4 * gg + r] =
                aD[nt][r] + dec_b[4 * gg + r];
        }
      }
      __syncthreads();   // redD region freed before hdnF writes
    }
    if (sub == NSUB) break;

    // ---- phase A: full hdn via MFMA; wave wq owns ho in [64wq, 64wq+64) ----
    f32x4 aA[4][4];
    #pragma unroll
    for (int mt = 0; mt < 4; ++mt)
      #pragma unroll
      for (int nt = 0; nt < 4; ++nt) aA[mt][nt] = (f32x4){0.f, 0.f, 0.f, 0.f};
    {
      const bf16x8* w1H = (const bf16x8*)(wsb + OFF_W1H);
      const bf16x8* w1L = (const bf16x8*)(wsb + OFF_W1L);
      #pragma unroll
      for (int kt = 0; kt < 8; ++kt) {
        bf16x8 wh[4], wl[4], zh[4], zl[4];
        #pragma unroll
        for (int mt = 0; mt < 4; ++mt) {
          int fi = ((wq * 4 + mt) * 8 + kt) * 64 + lane;
          wh[mt] = w1H[fi]; wl[mt] = w1L[fi];
        }
        #pragma unroll
        for (int nt = 0; nt < 4; ++nt) {
          int li = (kt * 4 + nt) * 64 + lane;
          zh[nt] = zHl[li]; zl[nt] = zLl[li];
        }
        #pragma unroll
        for (int mt = 0; mt < 4; ++mt)
          #pragma unroll
          for (int nt = 0; nt < 4; ++nt) {
            aA[mt][nt] = __builtin_amdgcn_mfma_f32_16x16x32_bf16(wh[mt], zh[nt], aA[mt][nt], 0, 0, 0);
            aA[mt][nt] = __builtin_amdgcn_mfma_f32_16x16x32_bf16(wh[mt], zl[nt], aA[mt][nt], 0, 0, 0);
            aA[mt][nt] = __builtin_amdgcn_mfma_f32_16x16x32_bf16(wl[mt], zh[nt], aA[mt][nt], 0, 0, 0);
          }
      }
    }
    // bias + relu + bsplit; in-wave repack: lane'=lane, e=r+4*(mt&1), kt2=2wq+(mt>>1)
    #pragma unroll
    for (int mt = 0; mt < 4; ++mt) {
      int kt2 = wq * 2 + (mt >> 1);
      #pragma unroll
      for (int nt = 0; nt < 4; ++nt) {
        ushort4 hi4, lo4;
        #pragma unroll
        for (int r = 0; r < 4; ++r) {
          float v = aA[mt][nt][r] + b1L[wq * 64 + mt * 16 + 4 * gg + r];
          v = fmaxf(v, 0.f);
          u16 h_, l_; bsplit(v, h_, l_);
          ((u16*)&hi4)[r] = h_; ((u16*)&lo4)[r] = l_;
        }
        int off = ((kt2 * 4 + nt) * 64 + lane) * 16 + 8 * (mt & 1);
        *(ushort4*)(smem + 65536 + off) = hi4;
        *(ushort4*)(smem + 98304 + off) = lo4;
      }
    }
    __syncthreads();   // all zF-LDS reads done -> redB may reuse that region

    // ---- phase B: [80col][64b] = W2^T-slab x hdn, persistent W2 frags ----
    f32x4 aB[5][4];
    #pragma unroll
    for (int mt = 0; mt < 5; ++mt)
      #pragma unroll
      for (int nt = 0; nt < 4; ++nt) aB[mt][nt] = (f32x4){0.f, 0.f, 0.f, 0.f};
    #pragma unroll
    for (int ktl = 0; ktl < 2; ++ktl) {
      int kt2 = wq * 2 + ktl;
      bf16x8 hh[4], hl2[4];
      #pragma unroll
      for (int nt = 0; nt < 4; ++nt) {
        int li = (kt2 * 4 + nt) * 64 + lane;
        hh[nt] = hHl[li]; hl2[nt] = hLl[li];
      }
      #pragma unroll
      for (int mt = 0; mt < 5; ++mt)
        #pragma unroll
        for (int nt = 0; nt < 4; ++nt) {
          aB[mt][nt] = __builtin_amdgcn_mfma_f32_16x16x32_bf16(wHi[ktl][mt], hh[nt],  aB[mt][nt], 0, 0, 0);
          aB[mt][nt] = __builtin_amdgcn_mfma_f32_16x16x32_bf16(wHi[ktl][mt], hl2[nt], aB[mt][nt], 0, 0, 0);
          aB[mt][nt] = __builtin_amdgcn_mfma_f32_16x16x32_bf16(wLo[ktl][mt], hh[nt],  aB[mt][nt], 0, 0, 0);
        }
    }

    // cross-wave K reduction + wave0 epilogue (R5-verified math)
    if (wq) {
      float* r = redB + ((wq - 1) * 64 + lane) * 84;
      #pragma unroll
      for (int mt = 0; mt < 5; ++mt)
        #pragma unroll
        for (int nt = 0; nt < 4; ++nt)
          *(f32x4*)(r + (mt * 4 + nt) * 4) = aB[mt][nt];
    }
    __syncthreads();
    if (wq == 0) {
      #pragma unroll
      for (int q = 0; q < 3; ++q) {
        const float* r = redB + (q * 64 + lane) * 84;
        #pragma unroll
        for (int mt = 0; mt < 5; ++mt)
          #pragma unroll
          for (int nt = 0; nt < 4; ++nt)
            aB[mt][nt] += *(const f32x4*)(r + (mt * 4 + nt) * 4);
      }
      float ph[4][4] = {{0.f,0.f,0.f,0.f},{0.f,0.f,0.f,0.f},{0.f,0.f,0.f,0.f},{0.f,0.f,0.f,0.f}};
      #pragma unroll
      for (int mt = 0; mt < 5; ++mt) {
        int row0 = mt * 16 + 4 * gg;
        float4 b2v = *(const float4*)&b2L[row0];
        int hmt = row0 / 20;
        int c0  = row0 - hmt * 20;
        #pragma unroll
        for (int nt = 0; nt < 4; ++nt) {
          int b_loc = nt * 16 + c16;
          float4 dxv = *(const float4*)(dXr + ((size_t)sub * 256 + bq * 64 + b_loc) * 20 + c0);
          f32x4 a = aB[mt][nt];
          float t0 = fast_tanh(a[0] + b2v.x);
          float t1 = fast_tanh(a[1] + b2v.y);
          float t2 = fast_tanh(a[2] + b2v.z);
          float t3 = fast_tanh(a[3] + b2v.w);
          float contrib = fmaf(t0, dxv.x, fmaf(t1, dxv.y, fmaf(t2, dxv.z, t3 * dxv.w)));
          #pragma unroll
          for (int h = 0; h < 4; ++h)
            ph[h][nt] += (hmt == h) ? contrib : 0.f;
        }
      }
      #pragma unroll
      for (int h = 0; h < 4; ++h)
        #pragma unroll
        for (int nt = 0; nt < 4; ++nt) {
          float v = ph[h][nt];
          v += __shfl_xor(v, 16);
          v += __shfl_xor(v, 32);
          ph[h][nt] = v;
        }
      // z update + frag-order stores (kt=j>>3, lane'=c16+16*(j&3), e=gg+4*((j>>2)&1))
      int kt = j >> 3;
      int lp = c16 + 16 * (j & 3);
      int e  = gg + 4 * ((j >> 2) & 1);
      size_t bofs = ((size_t)((sub + 1) & 1) * 4 + bq) * 16384;
      #pragma unroll
      for (int nt = 0; nt < 4; ++nt) {
        float val = (gg == 0) ? ph[0][nt] : (gg == 1) ? ph[1][nt]
                  : (gg == 2) ? ph[2][nt] : ph[3][nt];
        zreg[nt] += val;
        u16 h_, l_; bsplit(zreg[nt], h_, l_);
        int idx = ((kt * 4 + nt) * 64 + lp) * 8 + e;
        st_coh_u16(zFH + bofs + idx, h_);
        st_coh_u16(zFL + bofs + idx, l_);
      }
    }
    gbar(mycnt, bt); bt += 64;
  }
}

// ---------------------------------------------------------------------------
extern "C" void kernel_launch(void* const* d_in, const int* in_sizes, int n_in,
                              void* d_out, int out_size, void* d_ws, size_t ws_size,
                              hipStream_t stream) {
  const float* ts    = (const float*)d_in[0];
  const float* us    = (const float*)d_in[1];
  const float* enc_b = (const float*)d_in[5];
  const float* dec_W = (const float*)d_in[6];
  const float* dec_b = (const float*)d_in[7];
  const float* f_W1  = (const float*)d_in[8];
  const float* f_b1  = (const float*)d_in[9];
  const float* f_W2  = (const float*)d_in[10];
  const float* f_b2  = (const float*)d_in[11];
  float* out = (float*)d_out;
  char* wsb = (char*)d_ws;

  k_dx   <<<5080, 256, 0, stream>>>(ts, us, (float*)(wsb + OFF_DXR));
  k_w2f  <<<10240, 256, 0, stream>>>(f_W2, (u16*)(wsb + OFF_W2H), (u16*)(wsb + OFF_W2L));
  k_w1f  <<<256, 256, 0, stream>>>(f_W1, (u16*)(wsb + OFF_W1H), (u16*)(wsb + OFF_W1L));
  k_def  <<<16, 256, 0, stream>>>(dec_W, (u16*)(wsb + OFF_DEH), (u16*)(wsb + OFF_DEL));
  k_initF<<<256, 256, 0, stream>>>(enc_b, (u16*)(wsb + OFF_ZFH), (u16*)(wsb + OFF_ZFL));
  k_bar0 <<<1, 64, 0, stream>>>((u32*)(wsb + OFF_BAR));

  k_ode2<<<NBLK, 256, 0, stream>>>(wsb, f_b1, f_b2, dec_b, out);
}

// Round 8
// 4242.919 us; speedup vs baseline: 1.0493x; 1.0493x over previous
//
#include <hip/hip_runtime.h>
#include <hip/hip_bf16.h>
#include <cmath>

// L=128, B=256, H=256, C=17, Y=16, N_SUB=2
#define L_   128
#define B_   256
#define H_   256
#define C_   17
#define Y_   16
#define NSUB 254
#define NGRP 8           // groups (b-slabs of 32)
#define RNK  32          // ranks per group (8 h each)

typedef short bf16x8 __attribute__((ext_vector_type(8)));
typedef float f32x4  __attribute__((ext_vector_type(4)));
typedef unsigned short u16;
typedef unsigned int   u32;

// ---- workspace byte offsets ------------------------------------------------
#define OFF_DXR  0u           // [254][256 b][20 c] f32              5,201,920
#define OFF_W2H  5201920u     // [32 r][10 mt][8 kt][64][8] u16      2,621,440
#define OFF_W2L  7823360u     //                                     2,621,440
#define OFF_W1H  10444800u    // [16 mtg][8 kt][64][8] u16             131,072
#define OFF_W1L  10575872u    //                                       131,072
#define OFF_DEH  10706944u    // [8 kt][64][8] u16                       8,192
#define OFF_DEL  10715136u    //                                         8,192
#define OFF_ZFH  10723328u    // [2 buf][8 grp][8 kt][2 nt][64][8] u16 262,144
#define OFF_ZFL  10985472u    //                                       262,144
#define OFF_FLG  11247616u    // [8 grp][32 rank] u32 (128B line/grp)    1,024

__device__ __forceinline__ float fast_tanh(float x) {
  float e = __expf(2.0f * x);
  return 1.0f - __fdividef(2.0f, e + 1.0f);
}

__device__ __forceinline__ void bsplit(float x, u16& hi, u16& lo) {
  __hip_bfloat16 h = __float2bfloat16(x);
  float hf = __bfloat162float(h);
  __hip_bfloat16 l = __float2bfloat16(x - hf);
  hi = *(u16*)&h;
  lo = *(u16*)&l;
}

// ---- MALL-path (L1+L2 bypass) helpers — R5/R6-validated mechanism ----------
__device__ __forceinline__ void ld8_sc01(f32x4 r[8],
    const void* p0, const void* p1, const void* p2, const void* p3,
    const void* p4, const void* p5, const void* p6, const void* p7) {
  asm volatile(
    "global_load_dwordx4 %0, %8, off sc0 sc1\n\t"
    "global_load_dwordx4 %1, %9, off sc0 sc1\n\t"
    "global_load_dwordx4 %2, %10, off sc0 sc1\n\t"
    "global_load_dwordx4 %3, %11, off sc0 sc1\n\t"
    "global_load_dwordx4 %4, %12, off sc0 sc1\n\t"
    "global_load_dwordx4 %5, %13, off sc0 sc1\n\t"
    "global_load_dwordx4 %6, %14, off sc0 sc1\n\t"
    "global_load_dwordx4 %7, %15, off sc0 sc1\n\t"
    "s_waitcnt vmcnt(0)"
    : "=&v"(r[0]), "=&v"(r[1]), "=&v"(r[2]), "=&v"(r[3]),
      "=&v"(r[4]), "=&v"(r[5]), "=&v"(r[6]), "=&v"(r[7])
    : "v"(p0), "v"(p1), "v"(p2), "v"(p3), "v"(p4), "v"(p5), "v"(p6), "v"(p7)
    : "memory");
}

__device__ __forceinline__ void st_coh_u16(u16* p, u32 v) {
  asm volatile("global_store_short %0, %1, off sc0 sc1" :: "v"(p), "v"(v) : "memory");
}

// ---------------------------------------------------------------------------
// dXr[sub][b][c(20 pad)] = dX * (h/2)          (validated R4-R6)
__global__ void k_dx(const float* __restrict__ ts, const float* __restrict__ us,
                     float* __restrict__ dXr) {
  int idx = blockIdx.x * 256 + threadIdx.x;     // 1,300,480 exact
  int c   = idx % 20;
  int t2  = idx / 20;
  int b   = t2 & 255;
  int sub = t2 >> 8;
  if (c >= C_) { dXr[idx] = 0.f; return; }
  int s = sub >> 1, j = sub & 1;
  float t_s = ts[s * B_], t_n = ts[(s + 1) * B_];
  float h = t_n - t_s;
  float xi, xn;
  if (c == 0) { xi = ts[s * B_ + b]; xn = ts[(s + 1) * B_ + b]; }
  else {
    xi = us[(size_t)s       * 4096 + b * 16 + (c - 1)];
    xn = us[(size_t)(s + 1) * 4096 + b * 16 + (c - 1)];
  }
  float mn = (xn - xi) / h;
  float mi;
  if (s == 0) mi = mn;
  else {
    float hp = t_s - ts[(s - 1) * B_];
    float xp = (c == 0) ? ts[(s - 1) * B_ + b]
                        : us[(size_t)(s - 1) * 4096 + b * 16 + (c - 1)];
    mi = (xi - xp) / hp;
  }
  float c2 = 3.f * (xn - xi) / (h * h) - (2.f * mi + mn) / h;
  float c3 = 2.f * (xi - xn) / (h * h * h) + (mi + mn) / (h * h);
  float u  = j ? 0.5f * h : 0.f;
  float dX = mi + 2.f * c2 * u + 3.f * c3 * u * u;
  dXr[idx] = dX * 0.5f * h;
}

// ---------------------------------------------------------------------------
// W2 A-frags per rank: A[m=col(160: 8h x 20pad)][k=256], hi/lo planes.
__global__ void k_w2f(const float* __restrict__ W2,
                      u16* __restrict__ WH, u16* __restrict__ WL) {
  int idx = blockIdx.x * 256 + threadIdx.x;     // 1,310,720 (grid 5120)
  int e = idx & 7, lane = (idx >> 3) & 63, kt = (idx >> 9) & 7;
  int t = idx >> 12;
  int mt = t % 10, r = t / 10;
  int col = mt * 16 + (lane & 15);
  int hl = col / 20, c = col - hl * 20;
  int k = kt * 32 + 4 * (lane >> 4) + (e & 3) + 16 * (e >> 2);
  float v = (c < C_) ? W2[(size_t)k * (H_ * C_) + (r * 8 + hl) * C_ + c] : 0.f;
  u16 hi, lo; bsplit(v, hi, lo);
  WH[idx] = hi; WL[idx] = lo;
}

// W1 A-frags (full matrix): A[m=ho(256)][k=h_in(256)], [16 mtg][8 kt][64][8].
__global__ void k_w1f(const float* __restrict__ W1,
                      u16* __restrict__ WH, u16* __restrict__ WL) {
  int idx = blockIdx.x * 256 + threadIdx.x;     // 65536 (grid 256)
  int e = idx & 7, lane = (idx >> 3) & 63, kt = (idx >> 9) & 7, mtg = idx >> 12;
  int m = mtg * 16 + (lane & 15);
  int k = kt * 32 + 4 * (lane >> 4) + (e & 3) + 16 * (e >> 2);
  float v = W1[k * 256 + m];
  u16 hi, lo; bsplit(v, hi, lo);
  WH[idx] = hi; WL[idx] = lo;
}

// dec_W A-frags: A[m=y(16)][k=h(256)].
__global__ void k_def(const float* __restrict__ decW,
                      u16* __restrict__ DH, u16* __restrict__ DL) {
  int idx = blockIdx.x * 256 + threadIdx.x;     // 4096 (grid 16)
  int e = idx & 7, lane = (idx >> 3) & 63, kt = idx >> 9;
  int y = lane & 15;
  int k = kt * 32 + 4 * (lane >> 4) + (e & 3) + 16 * (e >> 2);
  float v = decW[k * 16 + y];
  u16 hi, lo; bsplit(v, hi, lo);
  DH[idx] = hi; DL[idx] = lo;
}

// z0 frags (buf0): [8 grp][8 kt][2 nt][64][8], z0[h][b] = enc_b[h].
__global__ void k_initF(const float* __restrict__ enc_b,
                        u16* __restrict__ ZH, u16* __restrict__ ZL) {
  int idx = blockIdx.x * 256 + threadIdx.x;     // 65536 (grid 256)
  int e = idx & 7, lane = (idx >> 3) & 63;
  int kt = (idx >> 10) & 7;
  int h = kt * 32 + 4 * (lane >> 4) + (e & 3) + 16 * (e >> 2);
  float v = enc_b[h];
  u16 hi, lo; bsplit(v, hi, lo);
  ZH[idx] = hi; ZL[idx] = lo;
}

// zero flags through the coherent point (runs every replay, stream-ordered)
__global__ void k_flg0(u32* f) {
  u32 z = 0;
  u32* p = f + threadIdx.x;                     // 256 = 8 grp x 32 rank
  asm volatile("global_store_dword %0, %1, off sc0 sc1" :: "v"(p), "v"(z) : "memory");
}

// ---------------------------------------------------------------------------
// Persistent kernel: 256 blocks. grp = blk>>5 owns b-slab [32*grp, 32*grp+32);
// rank = blk&31 owns h in [8*rank, 8*rank+8). NO placement assumptions.
// Per substep: poll group flags >= sub -> gather z frags (MALL) -> LDS ->
// decode (even) -> phase A (32x-redundant per group; wave kq computes exactly
// the ho-quarter it consumes) -> pure-register repack -> phase B (W2-hi
// persistent in VGPRs, W2-lo streamed from L2) -> redB reduce -> epilogue ->
// owner z-store (MALL) -> vmcnt(0) -> flag store. ONE barrier per substep.
__global__ __launch_bounds__(256, 1)
void k_ode4(char* __restrict__ wsb, const float* __restrict__ enc_b,
            const float* __restrict__ f_b1, const float* __restrict__ f_b2,
            const float* __restrict__ dec_b, float* __restrict__ out) {
  const int tid = threadIdx.x, lane = tid & 63, kq = tid >> 6;
  const int grp = blockIdx.x >> 5, rank = blockIdx.x & 31;
  const int gg = lane >> 4, c16 = lane & 15;

  // LDS: zstage hi [0,16K) lo [16K,32K) | red 80K [32K,112K+2K) | b1L | b2L
  __shared__ __align__(16) char smem[116352];
  float* b1L = (float*)(smem + 114688);         // 256 f32
  float* b2L = (float*)(smem + 115712);         // 160 f32

  b1L[tid] = f_b1[tid];
  if (tid < 160) { int hl = tid / 20, c = tid - hl * 20;
                   b2L[tid] = (c < C_) ? f_b2[(rank * 8 + hl) * C_ + c] : 0.f; }

  const bf16x8* W2Hg = (const bf16x8*)(wsb + OFF_W2H);
  const bf16x8* W2Lg = (const bf16x8*)(wsb + OFF_W2L);
  const bf16x8* W1Hg = (const bf16x8*)(wsb + OFF_W1H);
  const bf16x8* W1Lg = (const bf16x8*)(wsb + OFF_W1L);
  const bf16x8* DHg  = (const bf16x8*)(wsb + OFF_DEH);
  const bf16x8* DLg  = (const bf16x8*)(wsb + OFF_DEL);
  const float*  dXr  = (const float*)(wsb + OFF_DXR);
  u32* flg = (u32*)(wsb + OFF_FLG) + grp * 32;

  // persistent W2-hi frags: [2 ktl][10 mt] = 80 VGPR
  bf16x8 wHi[2][10];
  #pragma unroll
  for (int ktl = 0; ktl < 2; ++ktl)
    #pragma unroll
    for (int mt = 0; mt < 10; ++mt)
      wHi[ktl][mt] = W2Hg[((rank * 10 + mt) * 8 + kq * 2 + ktl) * 64 + lane];

  // fp32 master z (waves 0,1 = nt): z[rank*8+hh][grp*32 + kq*16 + c16]
  float zreg[8];
  if (kq < 2)
    #pragma unroll
    for (int hh = 0; hh < 8; ++hh) zreg[hh] = enc_b[rank * 8 + hh];

  for (int sub = 0; ; ++sub) {
    // ---- group barrier: wait all 32 ranks' flags >= sub (1 line, no atomics)
    if (kq == 0) {
      u32 guard = 0;
      for (;;) {
        u32 v;
        const u32* p = flg + (lane & 31);
        asm volatile("global_load_dword %0, %1, off sc0 sc1\n\ts_waitcnt vmcnt(0)"
                     : "=v"(v) : "v"(p) : "memory");
        if (__all((int)(v >= (u32)sub))) break;
        __builtin_amdgcn_s_sleep(1);
        if (++guard > (1u << 16)) break;        // fail-fast, no 600s hang
      }
    }
    __syncthreads();

    // ---- gather this wave's kt-pair of z frags (hi+lo), one batched RT ----
    {
      const f32x4* zh = (const f32x4*)(wsb + OFF_ZFH +
                          ((size_t)(sub & 1) * NGRP + grp) * 16384);
      const f32x4* zl = (const f32x4*)(wsb + OFF_ZFL +
                          ((size_t)(sub & 1) * NGRP + grp) * 16384);
      int f0 = ((2 * kq + 0) * 2 + 0) * 64 + lane;
      int f1 = ((2 * kq + 0) * 2 + 1) * 64 + lane;
      int f2 = ((2 * kq + 1) * 2 + 0) * 64 + lane;
      int f3 = ((2 * kq + 1) * 2 + 1) * 64 + lane;
      f32x4 r[8];
      ld8_sc01(r, zh + f0, zh + f1, zh + f2, zh + f3,
                  zl + f0, zl + f1, zl + f2, zl + f3);
      ((f32x4*)smem)[f0] = r[0];           ((f32x4*)smem)[f1] = r[1];
      ((f32x4*)smem)[f2] = r[2];           ((f32x4*)smem)[f3] = r[3];
      ((f32x4*)(smem + 16384))[f0] = r[4]; ((f32x4*)(smem + 16384))[f1] = r[5];
      ((f32x4*)(smem + 16384))[f2] = r[6]; ((f32x4*)(smem + 16384))[f3] = r[7];
    }
    __syncthreads();

    const bf16x8* zHl = (const bf16x8*)smem;
    const bf16x8* zLl = (const bf16x8*)(smem + 16384);
    f32x4* red4 = (f32x4*)(smem + 32768);

    // ---- decode (even subs): out[sub/2] = z @ decW + dec_b; rank0 stores ---
    if ((sub & 1) == 0) {
      f32x4 ad0 = (f32x4){0.f,0.f,0.f,0.f}, ad1 = (f32x4){0.f,0.f,0.f,0.f};
      #pragma unroll
      for (int ktl = 0; ktl < 2; ++ktl) {
        int kt = kq * 2 + ktl;
        bf16x8 dh = DHg[kt * 64 + lane], dl = DLg[kt * 64 + lane];
        bf16x8 zh0 = zHl[(kt * 2 + 0) * 64 + lane], zl0 = zLl[(kt * 2 + 0) * 64 + lane];
        bf16x8 zh1 = zHl[(kt * 2 + 1) * 64 + lane], zl1 = zLl[(kt * 2 + 1) * 64 + lane];
        ad0 = __builtin_amdgcn_mfma_f32_16x16x32_bf16(dh, zh0, ad0, 0, 0, 0);
        ad0 = __builtin_amdgcn_mfma_f32_16x16x32_bf16(dh, zl0, ad0, 0, 0, 0);
        ad0 = __builtin_amdgcn_mfma_f32_16x16x32_bf16(dl, zh0, ad0, 0, 0, 0);
        ad1 = __builtin_amdgcn_mfma_f32_16x16x32_bf16(dh, zh1, ad1, 0, 0, 0);
        ad1 = __builtin_amdgcn_mfma_f32_16x16x32_bf16(dh, zl1, ad1, 0, 0, 0);
        ad1 = __builtin_amdgcn_mfma_f32_16x16x32_bf16(dl, zh1, ad1, 0, 0, 0);
      }
      if (kq) {
        red4[((kq - 1) * 2 + 0) * 64 + lane] = ad0;
        red4[((kq - 1) * 2 + 1) * 64 + lane] = ad1;
      }
      __syncthreads();
      if (kq == 0 && rank == 0) {
        #pragma unroll
        for (int q = 0; q < 3; ++q) {
          ad0 += red4[(q * 2 + 0) * 64 + lane];
          ad1 += red4[(q * 2 + 1) * 64 + lane];
        }
        float4 q0, q1;
        q0.x = ad0[0] + dec_b[4 * gg + 0]; q0.y = ad0[1] + dec_b[4 * gg + 1];
        q0.z = ad0[2] + dec_b[4 * gg + 2]; q0.w = ad0[3] + dec_b[4 * gg + 3];
        q1.x = ad1[0] + dec_b[4 * gg + 0]; q1.y = ad1[1] + dec_b[4 * gg + 1];
        q1.z = ad1[2] + dec_b[4 * gg + 2]; q1.w = ad1[3] + dec_b[4 * gg + 3];
        size_t ro = (size_t)(sub >> 1) * 4096;
        *(float4*)(out + ro + (grp * 32 +      c16) * 16 + 4 * gg) = q0;
        *(float4*)(out + ro + (grp * 32 + 16 + c16) * 16 + 4 * gg) = q1;
      }
      __syncthreads();
    }
    if (sub == NSUB) break;

    // ---- phase A: wave kq computes hdn rows ho in [64kq, 64kq+64) ----
    f32x4 aa[4][2];
    #pragma unroll
    for (int mm = 0; mm < 4; ++mm) {
      aa[mm][0] = (f32x4){0.f,0.f,0.f,0.f};
      aa[mm][1] = (f32x4){0.f,0.f,0.f,0.f};
    }
    for (int kt = 0; kt < 8; ++kt) {
      bf16x8 zh0 = zHl[(kt * 2 + 0) * 64 + lane], zl0 = zLl[(kt * 2 + 0) * 64 + lane];
      bf16x8 zh1 = zHl[(kt * 2 + 1) * 64 + lane], zl1 = zLl[(kt * 2 + 1) * 64 + lane];
      #pragma unroll
      for (int mm = 0; mm < 4; ++mm) {
        bf16x8 wh = W1Hg[((4 * kq + mm) * 8 + kt) * 64 + lane];
        bf16x8 wl = W1Lg[((4 * kq + mm) * 8 + kt) * 64 + lane];
        aa[mm][0] = __builtin_amdgcn_mfma_f32_16x16x32_bf16(wh, zh0, aa[mm][0], 0, 0, 0);
        aa[mm][0] = __builtin_amdgcn_mfma_f32_16x16x32_bf16(wh, zl0, aa[mm][0], 0, 0, 0);
        aa[mm][0] = __builtin_amdgcn_mfma_f32_16x16x32_bf16(wl, zh0, aa[mm][0], 0, 0, 0);
        aa[mm][1] = __builtin_amdgcn_mfma_f32_16x16x32_bf16(wh, zh1, aa[mm][1], 0, 0, 0);
        aa[mm][1] = __builtin_amdgcn_mfma_f32_16x16x32_bf16(wh, zl1, aa[mm][1], 0, 0, 0);
        aa[mm][1] = __builtin_amdgcn_mfma_f32_16x16x32_bf16(wl, zh1, aa[mm][1], 0, 0, 0);
      }
    }

    // ---- pure-register repack: C(mm,nt) -> B-frag (kt2 = 2kq + mm>>1) ----
    bf16x8 hH[2][2], hL[2][2];
    #pragma unroll
    for (int mm = 0; mm < 4; ++mm)
      #pragma unroll
      for (int nt = 0; nt < 2; ++nt)
        #pragma unroll
        for (int r = 0; r < 4; ++r) {
          float v = aa[mm][nt][r] + b1L[kq * 64 + mm * 16 + 4 * gg + r];
          v = fmaxf(v, 0.f);
          u16 hi, lo; bsplit(v, hi, lo);
          hH[mm >> 1][nt][r + 4 * (mm & 1)] = (short)hi;
          hL[mm >> 1][nt][r + 4 * (mm & 1)] = (short)lo;
        }

    // ---- phase B: [160 col][32 b]; W2-hi persistent, W2-lo streamed ----
    f32x4 ab[10][2];
    #pragma unroll
    for (int mt = 0; mt < 10; ++mt) {
      ab[mt][0] = (f32x4){0.f,0.f,0.f,0.f};
      ab[mt][1] = (f32x4){0.f,0.f,0.f,0.f};
    }
    #pragma unroll
    for (int ktl = 0; ktl < 2; ++ktl)
      #pragma unroll
      for (int mt = 0; mt < 10; ++mt) {
        bf16x8 wlo = W2Lg[((rank * 10 + mt) * 8 + kq * 2 + ktl) * 64 + lane];
        ab[mt][0] = __builtin_amdgcn_mfma_f32_16x16x32_bf16(wHi[ktl][mt], hH[ktl][0], ab[mt][0], 0, 0, 0);
        ab[mt][0] = __builtin_amdgcn_mfma_f32_16x16x32_bf16(wHi[ktl][mt], hL[ktl][0], ab[mt][0], 0, 0, 0);
        ab[mt][0] = __builtin_amdgcn_mfma_f32_16x16x32_bf16(wlo,          hH[ktl][0], ab[mt][0], 0, 0, 0);
        ab[mt][1] = __builtin_amdgcn_mfma_f32_16x16x32_bf16(wHi[ktl][mt], hH[ktl][1], ab[mt][1], 0, 0, 0);
        ab[mt][1] = __builtin_amdgcn_mfma_f32_16x16x32_bf16(wHi[ktl][mt], hL[ktl][1], ab[mt][1], 0, 0, 0);
        ab[mt][1] = __builtin_amdgcn_mfma_f32_16x16x32_bf16(wlo,          hH[ktl][1], ab[mt][1], 0, 0, 0);
      }

    // ---- cross-wave K reduce (conflict-free lane*16 layout) ----
    #pragma unroll
    for (int mt = 0; mt < 10; ++mt) {
      red4[(kq * 20 + mt * 2 + 0) * 64 + lane] = ab[mt][0];
      red4[(kq * 20 + mt * 2 + 1) * 64 + lane] = ab[mt][1];
    }
    __syncthreads();

    // ---- epilogue on waves 0,1 (w = nt): tanh, c-contract, z update ----
    if (kq < 2) {
      const int w = kq;
      float ph[8] = {0.f,0.f,0.f,0.f,0.f,0.f,0.f,0.f};
      #pragma unroll
      for (int mt = 0; mt < 10; ++mt) {
        f32x4 s = red4[(0 * 20 + mt * 2 + w) * 64 + lane]
                + red4[(1 * 20 + mt * 2 + w) * 64 + lane]
                + red4[(2 * 20 + mt * 2 + w) * 64 + lane]
                + red4[(3 * 20 + mt * 2 + w) * 64 + lane];
        int col0 = mt * 16 + 4 * gg;
        int hl_  = col0 / 20;
        int c0   = col0 - hl_ * 20;
        float4 b2v = *(const float4*)&b2L[col0];
        float4 dxv = *(const float4*)(dXr +
            ((size_t)sub * 256 + grp * 32 + w * 16 + c16) * 20 + c0);
        float t0 = fast_tanh(s[0] + b2v.x);
        float t1 = fast_tanh(s[1] + b2v.y);
        float t2 = fast_tanh(s[2] + b2v.z);
        float t3 = fast_tanh(s[3] + b2v.w);
        float contrib = fmaf(t0, dxv.x, fmaf(t1, dxv.y, fmaf(t2, dxv.z, t3 * dxv.w)));
        #pragma unroll
        for (int hh = 0; hh < 8; ++hh)
          ph[hh] += (hl_ == hh) ? contrib : 0.f;
      }
      #pragma unroll
      for (int hh = 0; hh < 8; ++hh) {
        float v = ph[hh];
        v += __shfl_xor(v, 16);
        v += __shfl_xor(v, 32);
        zreg[hh] += v;
      }
      if (gg == 0) {
        u16* zph = (u16*)(wsb + OFF_ZFH + ((size_t)((sub + 1) & 1) * NGRP + grp) * 16384);
        u16* zpl = (u16*)(wsb + OFF_ZFL + ((size_t)((sub + 1) & 1) * NGRP + grp) * 16384);
        #pragma unroll
        for (int hh = 0; hh < 8; ++hh) {
          int hg = rank * 8 + hh;
          int kt2 = hg >> 5, kl = hg & 31;
          int lp = c16 + 16 * ((kl >> 2) & 3);
          int e  = (kl & 3) + 4 * ((kl >> 4) & 1);
          int fi = ((kt2 * 2 + w) * 64 + lp) * 8 + e;
          u16 hi, lo; bsplit(zreg[hh], hi, lo);
          st_coh_u16(zph + fi, hi);
          st_coh_u16(zpl + fi, lo);
        }
      }
    }

    // ---- arrive: drain stores, then flag = sub+1 ----
    asm volatile("s_waitcnt vmcnt(0)" ::: "memory");
    __syncthreads();
    if (tid == 0) {
      u32* p = flg + rank;
      u32 v = (u32)(sub + 1);
      asm volatile("global_store_dword %0, %1, off sc0 sc1" :: "v"(p), "v"(v) : "memory");
    }
  }
}

// ---------------------------------------------------------------------------
extern "C" void kernel_launch(void* const* d_in, const int* in_sizes, int n_in,
                              void* d_out, int out_size, void* d_ws, size_t ws_size,
                              hipStream_t stream) {
  const float* ts    = (const float*)d_in[0];
  const float* us    = (const float*)d_in[1];
  const float* enc_b = (const float*)d_in[5];
  const float* dec_W = (const float*)d_in[6];
  const float* dec_b = (const float*)d_in[7];
  const float* f_W1  = (const float*)d_in[8];
  const float* f_b1  = (const float*)d_in[9];
  const float* f_W2  = (const float*)d_in[10];
  const float* f_b2  = (const float*)d_in[11];
  float* out = (float*)d_out;
  char* wsb = (char*)d_ws;

  k_dx   <<<5080, 256, 0, stream>>>(ts, us, (float*)(wsb + OFF_DXR));
  k_w2f  <<<5120, 256, 0, stream>>>(f_W2, (u16*)(wsb + OFF_W2H), (u16*)(wsb + OFF_W2L));
  k_w1f  <<<256, 256, 0, stream>>>(f_W1, (u16*)(wsb + OFF_W1H), (u16*)(wsb + OFF_W1L));
  k_def  <<<16, 256, 0, stream>>>(dec_W, (u16*)(wsb + OFF_DEH), (u16*)(wsb + OFF_DEL));
  k_initF<<<256, 256, 0, stream>>>(enc_b, (u16*)(wsb + OFF_ZFH), (u16*)(wsb + OFF_ZFL));
  k_flg0 <<<1, 256, 0, stream>>>((u32*)(wsb + OFF_FLG));

  k_ode4<<<NGRP * RNK, 256, 0, stream>>>(wsb, enc_b, f_b1, f_b2, dec_b, out);
}